// Round 16
// baseline (141.481 us; speedup 1.0000x reference)
//
#include <hip/hip_runtime.h>
#include <hip/hip_bf16.h>

typedef __bf16 bf16_t;
typedef __bf16 bf16x8 __attribute__((ext_vector_type(8)));
typedef float  f32x4  __attribute__((ext_vector_type(4)));

static __device__ __forceinline__ f32x4 mfma16(bf16x8 a, bf16x8 b, f32x4 c) {
    return __builtin_amdgcn_mfma_f32_16x16x32_bf16(a, b, c, 0, 0, 0);
}

// ---------------------------------------------------------------------------
// sigma packs (R6-R15 HW-verified, UNCHANGED):
// h_phys(ht,p) = 32*(ht>>1) + 8*(p>>2) + 4*(ht&1) + (p&3). L1 MFMA output at
// lane (g,c), ht-pair (2ks,2ks+1) forms k-octet [32ks+8g..+7] of the L2
// A-fragment at the SAME lane.
// W1ef[(ht*64+l)*8+j]          = W1[128+8g+j][sig(ht,c)]
// W2f [((ks*16+ct)*64+l)*8+j]  = W2[32ks+8g+4*(j>>2)+(j&3)][ct*16+c]
// ---------------------------------------------------------------------------
__global__ void prep_pack(const float* __restrict__ W1, const float* __restrict__ W2,
                          bf16_t* __restrict__ W1ef, bf16_t* __restrict__ W2f) {
    int t = blockIdx.x * blockDim.x + threadIdx.x;
    int l = t & 63, g = l >> 4, c = l & 15;
    if (t < 1024) {
        int ht = t >> 6;
        int hcol = 32 * (ht >> 1) + 8 * (c >> 2) + 4 * (ht & 1) + (c & 3);
        #pragma unroll
        for (int j = 0; j < 8; ++j)
            W1ef[t * 8 + j] = (bf16_t)W1[(128 + 8 * g + j) * 256 + hcol];
    } else if (t < 1024 + 8192) {
        int t2 = t - 1024;
        int ks = t2 >> 10;
        int ct = (t2 >> 6) & 15;
        #pragma unroll
        for (int j = 0; j < 8; ++j) {
            int krow = 32 * ks + 8 * g + 4 * (j >> 2) + (j & 3);
            W2f[t2 * 8 + j] = (bf16_t)W2[krow * 256 + ct * 16 + c];
        }
    }
}

// ---------------------------------------------------------------------------
// Pib[b,i,h] = bf16( nodes[b,i,:] @ W1[0:128,h] + b1[h] )   (NOW bf16)
// Pjb[b,j,h] = bf16( nodes[b,j,:] @ W1[160:288,h] )
// ---------------------------------------------------------------------------
__global__ __launch_bounds__(256) void prep_pij(const float* __restrict__ nodes,
                                                const float* __restrict__ W1,
                                                const float* __restrict__ b1,
                                                bf16_t* __restrict__ Pib,
                                                bf16_t* __restrict__ Pjb) {
    int b = blockIdx.x >> 3;
    int q = blockIdx.x & 7;
    int h = threadIdx.x;
    const float* nb = nodes + (b * 64 + q * 8) * 128;
    float ai[8], aj[8];
    float bias = b1[h];
    #pragma unroll
    for (int ii = 0; ii < 8; ++ii) { ai[ii] = bias; aj[ii] = 0.f; }
    for (int d = 0; d < 128; ++d) {
        float wi = W1[d * 256 + h];
        float wj = W1[(160 + d) * 256 + h];
        #pragma unroll
        for (int ii = 0; ii < 8; ++ii) {
            float s = nb[ii * 128 + d];
            ai[ii] = fmaf(s, wi, ai[ii]);
            aj[ii] = fmaf(s, wj, aj[ii]);
        }
    }
    #pragma unroll
    for (int ii = 0; ii < 8; ++ii) {
        Pib[(b * 64 + q * 8 + ii) * 256 + h] = (bf16_t)ai[ii];
        Pjb[(b * 64 + q * 8 + ii) * 256 + h] = (bf16_t)aj[ii];
    }
}

// ---------------------------------------------------------------------------
// v16 == v8 (88 us champion; critical-path hoists wf/pjb/edge-prefetch kept
// VERBATIM) with ~24 arch regs trimmed OFF the critical path so combined
// arch+AGPR ~120 <= 128 -> 4 waves/SIMD (R8 was 144 -> 2 waves/SIMD):
//   (1) Pi prefetch f32x4 x4 (16 regs) -> bf16x8 x2 (8 regs)   [Pib]
//   (2) b2/W3 epilogue constants laundered -> per-batch reloads (-16 regs,
//       issued at phase-B top, hidden under the 64-MFMA cluster)
// 512 blocks x 512 thr, 16 batches of 64 pairs, 1 barrier/batch.
// ---------------------------------------------------------------------------
__global__ __launch_bounds__(512, 2) void mlp_main(
    const float* __restrict__ edges,
    const bf16_t* __restrict__ Pib, const bf16_t* __restrict__ Pjb,
    const bf16_t* __restrict__ W1ef, const bf16_t* __restrict__ W2f,
    const float* __restrict__ b2, const float* __restrict__ W3,
    const float* __restrict__ b3, float* __restrict__ out) {

    __shared__ bf16_t a1f[2][16384];      // 2 x 32 KB fragment-linear a1
    __shared__ bf16_t elds[2][2048];      // 2 x 4 KB edge fragments (bf16)
    __shared__ float part[2][8][64];      // 2 x 2 KB partial h-sums

    const int p = blockIdx.x;
    const int xb = (p & 7) * 64 + (p >> 3);    // XCD swizzle (512 % 8 == 0)
    const int tid = threadIdx.x;
    const int w = tid >> 6, l = tid & 63, g = l >> 4, c = l & 15;
    const int b = xb >> 2;
    const f32x4 z4 = {0.f, 0.f, 0.f, 0.f};

    // ---- hoisted invariants (critical path — kept in registers, as R8) ----
    bf16x8 wf[2];                          // W1e frags, ht = 2w, 2w+1
    #pragma unroll
    for (int z = 0; z < 2; ++z)
        wf[z] = *(const bf16x8*)&W1ef[((2 * w + z) * 64 + l) * 8];

    bf16x8 pjb[4];                         // Pj octets: block-invariant (b fixed)
    #pragma unroll
    for (int pt = 0; pt < 4; ++pt)
        pjb[pt] = *(const bf16x8*)&Pjb[((long)(b * 64 + 16 * pt + c)) * 256
                                       + 32 * w + 8 * g];

    const float bias3 = b3[0];

    // laundered epilogue-constant bases (off critical path; forces per-batch
    // reload -> frees 16 long-lived regs that LICM would otherwise pin)
    const float* b2L = b2;
    const float* w3L = W3;

    // stage mapping: tid<256 stages unit u=tid: (spt, sg, sc)
    const int spt = tid >> 6, sg = (tid >> 4) & 3, sc = tid & 15;
    const long erowbase = (long)xb * 1024 + 16 * spt + sc;

    f32x4 es0, es1;                        // in-flight staged edges
    if (tid < 256) {
        const float* ep = edges + erowbase * 32 + 8 * sg;
        es0 = *(const f32x4*)ep; es1 = *(const f32x4*)(ep + 4);
    }
    const bf16_t* PiB = Pib + ((long)xb * 16) * 256 + 32 * w + 8 * g;
    bf16x8 pva = *(const bf16x8*)PiB;      // Pi octet for batch 0 (bf16, 4 regs)

    if (tid < 256) {                       // write batch-0 edges
        bf16x8 ev;
        #pragma unroll
        for (int j = 0; j < 4; ++j) { ev[j] = (bf16_t)es0[j]; ev[4 + j] = (bf16_t)es1[j]; }
        *(bf16x8*)&elds[0][tid * 8] = ev;
    }
    __syncthreads();

    bf16x8 pvb;

    for (int t = 0; t < 16; ++t) {
        const int cur = t & 1;

        asm volatile("" : "+s"(b2L), "+s"(w3L));   // block LICM of b2q/w3q

        // issue next batch's loads early (hidden under L1+L2 of batch t)
        if (t < 15) {
            if (tid < 256) {
                const float* ep = edges + (erowbase + 64 * (t + 1)) * 32 + 8 * sg;
                es0 = *(const f32x4*)ep; es1 = *(const f32x4*)(ep + 4);
            }
            pvb = *(const bf16x8*)(PiB + (t + 1) * 256);
        }

        // ---------------- layer 1 (sigma-fused, reg -> LDS octets) ----------
        {
            bf16x8 ebf[4];
            #pragma unroll
            for (int pt = 0; pt < 4; ++pt)
                ebf[pt] = *(const bf16x8*)&elds[cur][(pt * 64 + l) * 8];
            #pragma unroll
            for (int pt = 0; pt < 4; ++pt) {
                bf16x8 o;
                #pragma unroll
                for (int z = 0; z < 2; ++z) {
                    f32x4 a = mfma16(wf[z], ebf[pt], z4);
                    #pragma unroll
                    for (int r = 0; r < 4; ++r) {
                        float v = a[r] + (float)pva[4 * z + r] + (float)pjb[pt][4 * z + r];
                        v = v > 0.f ? v : 0.f;
                        o[4 * z + r] = (bf16_t)v;
                    }
                }
                *(bf16x8*)&a1f[cur][((pt * 8 + w) * 64 + l) * 8] = o;
            }
        }

        // write-late: staged edges for batch t+1 into the other elds buffer
        if (t < 15 && tid < 256) {
            bf16x8 ev;
            #pragma unroll
            for (int j = 0; j < 4; ++j) { ev[j] = (bf16_t)es0[j]; ev[4 + j] = (bf16_t)es1[j]; }
            *(bf16x8*)&elds[cur ^ 1][tid * 8] = ev;
        }
        __syncthreads();                   // the one barrier per batch

        // deferred out-write for batch t-1 (all waves' part complete)
        if (t > 0 && tid < 64) {
            float s = bias3;
            #pragma unroll
            for (int ww = 0; ww < 8; ++ww) s += part[cur ^ 1][ww][tid];
            out[(long)xb * 1024 + (t - 1) * 64 + tid] = s;
        }

        // ---------------- layer 2 + layer 3 ----------------
        {
            f32x4 acc2[4][2];
            #pragma unroll
            for (int pt = 0; pt < 4; ++pt) { acc2[pt][0] = z4; acc2[pt][1] = z4; }
            #pragma unroll
            for (int ks = 0; ks < 8; ++ks) {
                bf16x8 af[4];
                #pragma unroll
                for (int pt = 0; pt < 4; ++pt)
                    af[pt] = *(const bf16x8*)&a1f[cur][((pt * 8 + ks) * 64 + l) * 8];
                #pragma unroll
                for (int cc = 0; cc < 2; ++cc) {
                    bf16x8 w2 = *(const bf16x8*)&W2f[((ks * 16 + 2 * w + cc) * 64 + l) * 8];
                    #pragma unroll
                    for (int pt = 0; pt < 4; ++pt)
                        acc2[pt][cc] = mfma16(w2, af[pt], acc2[pt][cc]);
                }
            }
            // L3: col = 32w + 16cc + 4g + r (in-lane), pair = 16pt + c
            f32x4 b2q[2], w3q[2];
            #pragma unroll
            for (int cc = 0; cc < 2; ++cc) {
                b2q[cc] = *(const f32x4*)&b2L[32 * w + 16 * cc + 4 * g];
                w3q[cc] = *(const f32x4*)&w3L[32 * w + 16 * cc + 4 * g];
            }
            #pragma unroll
            for (int pt = 0; pt < 4; ++pt) {
                float s = 0.f;
                #pragma unroll
                for (int cc = 0; cc < 2; ++cc)
                    #pragma unroll
                    for (int r = 0; r < 4; ++r) {
                        float v = acc2[pt][cc][r] + b2q[cc][r];
                        v = v > 0.f ? v : 0.f;
                        s = fmaf(v, w3q[cc][r], s);
                    }
                s += __shfl_xor(s, 16);    // sum the 4 g-groups
                s += __shfl_xor(s, 32);
                if (g == 0) part[cur][w][pt * 16 + c] = s;
            }
        }
        pva = pvb;
    }

    __syncthreads();
    if (tid < 64) {                        // out for batch 15
        float s = bias3;
        #pragma unroll
        for (int ww = 0; ww < 8; ++ww) s += part[1][ww][tid];
        out[(long)xb * 1024 + 15 * 64 + tid] = s;
    }
}

extern "C" void kernel_launch(void* const* d_in, const int* in_sizes, int n_in,
                              void* d_out, int out_size, void* d_ws, size_t ws_size,
                              hipStream_t stream) {
    const float* nodes = (const float*)d_in[0];
    const float* edges = (const float*)d_in[1];
    const float* W1    = (const float*)d_in[2];
    const float* b1    = (const float*)d_in[3];
    const float* W2    = (const float*)d_in[4];
    const float* b2    = (const float*)d_in[5];
    const float* W3    = (const float*)d_in[6];
    const float* b3    = (const float*)d_in[7];
    float* out = (float*)d_out;

    char* ws = (char*)d_ws;
    bf16_t* Pib  = (bf16_t*)ws;                                       // 4 MB
    bf16_t* Pjb  = (bf16_t*)(ws + (size_t)4 * 1024 * 1024);           // 4 MB
    bf16_t* W2f  = (bf16_t*)(ws + (size_t)8 * 1024 * 1024);           // 128 KB
    bf16_t* W1ef = (bf16_t*)(ws + (size_t)8 * 1024 * 1024 + 131072);  // 16 KB

    prep_pack<<<dim3(36), dim3(256), 0, stream>>>(W1, W2, W1ef, W2f);
    prep_pij<<<dim3(1024), dim3(256), 0, stream>>>(nodes, W1, b1, Pib, Pjb);
    mlp_main<<<dim3(512), dim3(512), 0, stream>>>(edges, Pib, Pjb, W1ef, W2f, b2, W3, b3, out);
}

// Round 17
// 110.398 us; speedup vs baseline: 1.2816x; 1.2816x over previous
//
#include <hip/hip_runtime.h>
#include <hip/hip_bf16.h>

typedef __bf16 bf16_t;
typedef __bf16 bf16x8 __attribute__((ext_vector_type(8)));
typedef float  f32x4  __attribute__((ext_vector_type(4)));

static __device__ __forceinline__ f32x4 mfma16(bf16x8 a, bf16x8 b, f32x4 c) {
    return __builtin_amdgcn_mfma_f32_16x16x32_bf16(a, b, c, 0, 0, 0);
}

// ---------------------------------------------------------------------------
// sigma packs (R6-R16 HW-verified, UNCHANGED):
// h_phys(ht,p) = 32*(ht>>1) + 8*(p>>2) + 4*(ht&1) + (p&3). L1 MFMA output at
// lane (g,c), ht-pair (2ks,2ks+1) forms k-octet [32ks+8g..+7] of the L2
// A-fragment at the SAME lane.
// W1ef[(ht*64+l)*8+j]          = W1[128+8g+j][sig(ht,c)]
// W2f [((ks*16+ct)*64+l)*8+j]  = W2[32ks+8g+4*(j>>2)+(j&3)][ct*16+c]
// ---------------------------------------------------------------------------
__global__ void prep_pack(const float* __restrict__ W1, const float* __restrict__ W2,
                          bf16_t* __restrict__ W1ef, bf16_t* __restrict__ W2f) {
    int t = blockIdx.x * blockDim.x + threadIdx.x;
    int l = t & 63, g = l >> 4, c = l & 15;
    if (t < 1024) {
        int ht = t >> 6;
        int hcol = 32 * (ht >> 1) + 8 * (c >> 2) + 4 * (ht & 1) + (c & 3);
        #pragma unroll
        for (int j = 0; j < 8; ++j)
            W1ef[t * 8 + j] = (bf16_t)W1[(128 + 8 * g + j) * 256 + hcol];
    } else if (t < 1024 + 8192) {
        int t2 = t - 1024;
        int ks = t2 >> 10;
        int ct = (t2 >> 6) & 15;
        #pragma unroll
        for (int j = 0; j < 8; ++j) {
            int krow = 32 * ks + 8 * g + 4 * (j >> 2) + (j & 3);
            W2f[t2 * 8 + j] = (bf16_t)W2[krow * 256 + ct * 16 + c];
        }
    }
}

// ---------------------------------------------------------------------------
// Pi[b,i,h] = nodes[b,i,:] @ W1[0:128,h] + b1[h]   (f32, as R8)
// Pjb[b,j,h] = bf16( nodes[b,j,:] @ W1[160:288,h] )
// 1024 blocks x 8 rows (R10 fast version).
// ---------------------------------------------------------------------------
__global__ __launch_bounds__(256) void prep_pij(const float* __restrict__ nodes,
                                                const float* __restrict__ W1,
                                                const float* __restrict__ b1,
                                                float* __restrict__ Pi,
                                                bf16_t* __restrict__ Pjb) {
    int b = blockIdx.x >> 3;
    int q = blockIdx.x & 7;
    int h = threadIdx.x;
    const float* nb = nodes + (b * 64 + q * 8) * 128;
    float ai[8], aj[8];
    float bias = b1[h];
    #pragma unroll
    for (int ii = 0; ii < 8; ++ii) { ai[ii] = bias; aj[ii] = 0.f; }
    for (int d = 0; d < 128; ++d) {
        float wi = W1[d * 256 + h];
        float wj = W1[(160 + d) * 256 + h];
        #pragma unroll
        for (int ii = 0; ii < 8; ++ii) {
            float s = nb[ii * 128 + d];
            ai[ii] = fmaf(s, wi, ai[ii]);
            aj[ii] = fmaf(s, wj, aj[ii]);
        }
    }
    #pragma unroll
    for (int ii = 0; ii < 8; ++ii) {
        Pi[(b * 64 + q * 8 + ii) * 256 + h] = ai[ii];
        Pjb[(b * 64 + q * 8 + ii) * 256 + h] = (bf16_t)aj[ii];
    }
}

// ---------------------------------------------------------------------------
// v17 == v8 (88 us champion: same layouts, registers, hoists, 1 barrier/batch)
// with the loop ROTATED so phaseB(t) and phaseA(t+1) are adjacent straight-
// line code in one basic block: the scheduler can interleave B's 64-MFMA
// cluster with A's independent ds_reads/MFMAs/Pi-loads, filling the
// dependency stalls that cap R8 at ~30% on every pipe (2 waves/SIMD).
// 512 blocks x 512 thr, 16 batches of 64 pairs.
// ---------------------------------------------------------------------------
__global__ __launch_bounds__(512, 2) void mlp_main(
    const float* __restrict__ edges,
    const float* __restrict__ Pi, const bf16_t* __restrict__ Pjb,
    const bf16_t* __restrict__ W1ef, const bf16_t* __restrict__ W2f,
    const float* __restrict__ b2, const float* __restrict__ W3,
    const float* __restrict__ b3, float* __restrict__ out) {

    __shared__ bf16_t a1f[2][16384];      // 2 x 32 KB fragment-linear a1
    __shared__ bf16_t elds[2][2048];      // 2 x 4 KB edge fragments (bf16)
    __shared__ float part[2][8][64];      // 2 x 2 KB partial h-sums

    const int p = blockIdx.x;
    const int xb = (p & 7) * 64 + (p >> 3);    // XCD swizzle (512 % 8 == 0)
    const int tid = threadIdx.x;
    const int w = tid >> 6, l = tid & 63, g = l >> 4, c = l & 15;
    const int b = xb >> 2;
    const f32x4 z4 = {0.f, 0.f, 0.f, 0.f};
    const float bias3 = b3[0];
    const long outbase = (long)xb * 1024;

    // ---- hoisted invariants (as R8; 1 block/CU -> registers are free) ----
    bf16x8 wf[2];
    #pragma unroll
    for (int z = 0; z < 2; ++z)
        wf[z] = *(const bf16x8*)&W1ef[((2 * w + z) * 64 + l) * 8];

    bf16x8 pjb[4];
    #pragma unroll
    for (int pt = 0; pt < 4; ++pt)
        pjb[pt] = *(const bf16x8*)&Pjb[((long)(b * 64 + 16 * pt + c)) * 256
                                       + 32 * w + 8 * g];

    const float* PiB = Pi + ((long)xb * 16) * 256 + 32 * w + 8 * g;

    const int spt = tid >> 6, sg = (tid >> 4) & 3, sc = tid & 15;
    const long erowbase = (long)xb * 1024 + 16 * spt + sc;

    auto PHASE_A = [&](int tt, int buf) {   // elds[buf] + Pi(tt) -> a1f[buf]
        const float* pp = PiB + tt * 256;
        f32x4 pva0 = *(const f32x4*)pp;
        f32x4 pva1 = *(const f32x4*)(pp + 4);
        bf16x8 ebf[4];
        #pragma unroll
        for (int pt = 0; pt < 4; ++pt)
            ebf[pt] = *(const bf16x8*)&elds[buf][(pt * 64 + l) * 8];
        #pragma unroll
        for (int pt = 0; pt < 4; ++pt) {
            bf16x8 o;
            #pragma unroll
            for (int z = 0; z < 2; ++z) {
                f32x4 a = mfma16(wf[z], ebf[pt], z4);
                f32x4 pv = z ? pva1 : pva0;
                #pragma unroll
                for (int r = 0; r < 4; ++r) {
                    float v = a[r] + pv[r] + (float)pjb[pt][4 * z + r];
                    v = v > 0.f ? v : 0.f;
                    o[4 * z + r] = (bf16_t)v;
                }
            }
            *(bf16x8*)&a1f[buf][((pt * 8 + w) * 64 + l) * 8] = o;
        }
    };

    auto PHASE_B = [&](int buf) {           // a1f[buf] -> part[buf]
        f32x4 acc2[4][2];
        #pragma unroll
        for (int pt = 0; pt < 4; ++pt) { acc2[pt][0] = z4; acc2[pt][1] = z4; }
        #pragma unroll
        for (int ks = 0; ks < 8; ++ks) {
            bf16x8 af[4];
            #pragma unroll
            for (int pt = 0; pt < 4; ++pt)
                af[pt] = *(const bf16x8*)&a1f[buf][((pt * 8 + ks) * 64 + l) * 8];
            #pragma unroll
            for (int cc = 0; cc < 2; ++cc) {
                bf16x8 w2 = *(const bf16x8*)&W2f[((ks * 16 + 2 * w + cc) * 64 + l) * 8];
                #pragma unroll
                for (int pt = 0; pt < 4; ++pt)
                    acc2[pt][cc] = mfma16(w2, af[pt], acc2[pt][cc]);
            }
        }
        f32x4 b2q[2], w3q[2];
        #pragma unroll
        for (int cc = 0; cc < 2; ++cc) {
            b2q[cc] = *(const f32x4*)&b2[32 * w + 16 * cc + 4 * g];
            w3q[cc] = *(const f32x4*)&W3[32 * w + 16 * cc + 4 * g];
        }
        #pragma unroll
        for (int pt = 0; pt < 4; ++pt) {
            float s = 0.f;
            #pragma unroll
            for (int cc = 0; cc < 2; ++cc)
                #pragma unroll
                for (int r = 0; r < 4; ++r) {
                    float v = acc2[pt][cc][r] + b2q[cc][r];
                    v = v > 0.f ? v : 0.f;
                    s = fmaf(v, w3q[cc][r], s);
                }
            s += __shfl_xor(s, 16);
            s += __shfl_xor(s, 32);
            if (g == 0) part[buf][w][pt * 16 + c] = s;
        }
    };

    // ---- prologue: elds[0], es(batch1) ----
    f32x4 es0, es1;
    if (tid < 256) {
        const float* ep = edges + erowbase * 32 + 8 * sg;
        f32x4 a0 = *(const f32x4*)ep, a1 = *(const f32x4*)(ep + 4);
        bf16x8 ev;
        #pragma unroll
        for (int j = 0; j < 4; ++j) { ev[j] = (bf16_t)a0[j]; ev[4 + j] = (bf16_t)a1[j]; }
        *(bf16x8*)&elds[0][tid * 8] = ev;
        const float* ep1 = edges + (erowbase + 64) * 32 + 8 * sg;
        es0 = *(const f32x4*)ep1; es1 = *(const f32x4*)(ep1 + 4);
    }
    __syncthreads();                       // elds[0] visible

    PHASE_A(0, 0);                         // batch 0 -> a1f[0]
    if (tid < 256) {                       // elds[1] (batch 1); readers cross BAR(0)
        bf16x8 ev;
        #pragma unroll
        for (int j = 0; j < 4; ++j) { ev[j] = (bf16_t)es0[j]; ev[4 + j] = (bf16_t)es1[j]; }
        *(bf16x8*)&elds[1][tid * 8] = ev;
    }

    // ---- rotated main loop: BAR; out; [phaseB(t) || phaseA(t+1)]; stage ----
    for (int t = 0; t < 15; ++t) {
        __syncthreads();                   // BAR(t): a1f[t&1], elds[(t+1)&1] ready
        const int cur = t & 1;
        if (t < 14 && tid < 256) {         // issue es(batch t+2)
            const float* ep = edges + (erowbase + 64 * (t + 2)) * 32 + 8 * sg;
            es0 = *(const f32x4*)ep; es1 = *(const f32x4*)(ep + 4);
        }
        if (t > 0 && tid < 64) {           // out(t-1) from part[(t-1)&1]
            float s = bias3;
            #pragma unroll
            for (int ww = 0; ww < 8; ++ww) s += part[cur ^ 1][ww][tid];
            out[outbase + (t - 1) * 64 + tid] = s;
        }
        PHASE_B(cur);                      // batch t      (straight-line,
        PHASE_A(t + 1, cur ^ 1);           // batch t+1     interleavable)
        if (t < 14 && tid < 256) {         // elds[(t+2)&1] == elds[cur]
            bf16x8 ev;
            #pragma unroll
            for (int j = 0; j < 4; ++j) { ev[j] = (bf16_t)es0[j]; ev[4 + j] = (bf16_t)es1[j]; }
            *(bf16x8*)&elds[cur][tid * 8] = ev;
        }
    }

    __syncthreads();                       // a1f[1] (batch 15), part[0] ready
    if (tid < 64) {                        // out(14)
        float s = bias3;
        #pragma unroll
        for (int ww = 0; ww < 8; ++ww) s += part[0][ww][tid];
        out[outbase + 14 * 64 + tid] = s;
    }
    PHASE_B(1);                            // batch 15 -> part[1]
    __syncthreads();
    if (tid < 64) {                        // out(15)
        float s = bias3;
        #pragma unroll
        for (int ww = 0; ww < 8; ++ww) s += part[1][ww][tid];
        out[outbase + 15 * 64 + tid] = s;
    }
}

extern "C" void kernel_launch(void* const* d_in, const int* in_sizes, int n_in,
                              void* d_out, int out_size, void* d_ws, size_t ws_size,
                              hipStream_t stream) {
    const float* nodes = (const float*)d_in[0];
    const float* edges = (const float*)d_in[1];
    const float* W1    = (const float*)d_in[2];
    const float* b1    = (const float*)d_in[3];
    const float* W2    = (const float*)d_in[4];
    const float* b2    = (const float*)d_in[5];
    const float* W3    = (const float*)d_in[6];
    const float* b3    = (const float*)d_in[7];
    float* out = (float*)d_out;

    char* ws = (char*)d_ws;
    float*  Pi   = (float*)ws;                                        // 8 MB
    bf16_t* Pjb  = (bf16_t*)(ws + (size_t)8 * 1024 * 1024);           // 4 MB
    bf16_t* W2f  = (bf16_t*)(ws + (size_t)12 * 1024 * 1024);          // 128 KB
    bf16_t* W1ef = (bf16_t*)(ws + (size_t)12 * 1024 * 1024 + 131072); // 16 KB

    prep_pack<<<dim3(36), dim3(256), 0, stream>>>(W1, W2, W1ef, W2f);
    prep_pij<<<dim3(1024), dim3(256), 0, stream>>>(nodes, W1, b1, Pi, Pjb);
    mlp_main<<<dim3(512), dim3(512), 0, stream>>>(edges, Pi, Pjb, W1ef, W2f, b2, W3, b3, out);
}

// Round 18
// 101.739 us; speedup vs baseline: 1.3906x; 1.0851x over previous
//
#include <hip/hip_runtime.h>
#include <hip/hip_bf16.h>

typedef __bf16 bf16_t;
typedef __bf16 bf16x8 __attribute__((ext_vector_type(8)));
typedef float  f32x4  __attribute__((ext_vector_type(4)));

static __device__ __forceinline__ f32x4 mfma16(bf16x8 a, bf16x8 b, f32x4 c) {
    return __builtin_amdgcn_mfma_f32_16x16x32_bf16(a, b, c, 0, 0, 0);
}

// ---------------------------------------------------------------------------
// sigma packs (R6-R17 HW-verified):
// h_phys(ht,p) = 32*(ht>>1) + 8*(p>>2) + 4*(ht&1) + (p&3). L1 MFMA output at
// lane (g,c), ht-pair (2ks,2ks+1) forms k-octet [32ks+8g..+7] of the L2
// A-fragment at the SAME lane.
// W1ef[(ht*64+l)*8+j]          = W1[128+8g+j][sig(ht,c)]
// W2f [((ks*16+ct)*64+l)*8+j]  = W2[32ks+8g+4*(j>>2)+(j&3)][ct*16+c]
// ---------------------------------------------------------------------------
__global__ void prep_pack(const float* __restrict__ W1, const float* __restrict__ W2,
                          bf16_t* __restrict__ W1ef, bf16_t* __restrict__ W2f) {
    int t = blockIdx.x * blockDim.x + threadIdx.x;
    int l = t & 63, g = l >> 4, c = l & 15;
    if (t < 1024) {
        int ht = t >> 6;
        int hcol = 32 * (ht >> 1) + 8 * (c >> 2) + 4 * (ht & 1) + (c & 3);
        #pragma unroll
        for (int j = 0; j < 8; ++j)
            W1ef[t * 8 + j] = (bf16_t)W1[(128 + 8 * g + j) * 256 + hcol];
    } else if (t < 1024 + 8192) {
        int t2 = t - 1024;
        int ks = t2 >> 10;
        int ct = (t2 >> 6) & 15;
        #pragma unroll
        for (int j = 0; j < 8; ++j) {
            int krow = 32 * ks + 8 * g + 4 * (j >> 2) + (j & 3);
            W2f[t2 * 8 + j] = (bf16_t)W2[krow * 256 + ct * 16 + c];
        }
    }
}

// ---------------------------------------------------------------------------
// Pi[b,i,h] = nodes[b,i,:] @ W1[0:128,h] + b1[h]   (f32)
// Pjb[b,j,h] = bf16( nodes[b,j,:] @ W1[160:288,h] )
// 1024 blocks x 8 rows (R10 fast version: latency-bound, more blocks wins).
// ---------------------------------------------------------------------------
__global__ __launch_bounds__(256) void prep_pij(const float* __restrict__ nodes,
                                                const float* __restrict__ W1,
                                                const float* __restrict__ b1,
                                                float* __restrict__ Pi,
                                                bf16_t* __restrict__ Pjb) {
    int b = blockIdx.x >> 3;
    int q = blockIdx.x & 7;
    int h = threadIdx.x;
    const float* nb = nodes + (b * 64 + q * 8) * 128;
    float ai[8], aj[8];
    float bias = b1[h];
    #pragma unroll
    for (int ii = 0; ii < 8; ++ii) { ai[ii] = bias; aj[ii] = 0.f; }
    for (int d = 0; d < 128; ++d) {
        float wi = W1[d * 256 + h];
        float wj = W1[(160 + d) * 256 + h];
        #pragma unroll
        for (int ii = 0; ii < 8; ++ii) {
            float s = nb[ii * 128 + d];
            ai[ii] = fmaf(s, wi, ai[ii]);
            aj[ii] = fmaf(s, wj, aj[ii]);
        }
    }
    #pragma unroll
    for (int ii = 0; ii < 8; ++ii) {
        Pi[(b * 64 + q * 8 + ii) * 256 + h] = ai[ii];
        Pjb[(b * 64 + q * 8 + ii) * 256 + h] = (bf16_t)aj[ii];
    }
}

// ---------------------------------------------------------------------------
// FINAL: v8 mlp_main verbatim (88 us champion; best of 10 structural
// variants A/B-tested in R9-R17: producer/consumer, setprio, fat-wave,
// reg-trim occupancy, loop rotation all measured worse).
// 512 blocks x 512 thr, 16 batches of 64 pairs, 1 barrier/batch.
// L1 sigma-fused (a1 reg->LDS octets, conflict-free); L2 8-wave h-split with
// W2f streamed from L2$; in-lane L3 + 2 shfl; edge staging issue-early/
// write-late; Pi prefetched one batch ahead; out deferred one batch.
// ---------------------------------------------------------------------------
__global__ __launch_bounds__(512, 2) void mlp_main(
    const float* __restrict__ edges,
    const float* __restrict__ Pi, const bf16_t* __restrict__ Pjb,
    const bf16_t* __restrict__ W1ef, const bf16_t* __restrict__ W2f,
    const float* __restrict__ b2, const float* __restrict__ W3,
    const float* __restrict__ b3, float* __restrict__ out) {

    __shared__ bf16_t a1f[2][16384];      // 2 x 32 KB fragment-linear a1
    __shared__ bf16_t elds[2][2048];      // 2 x 4 KB edge fragments (bf16)
    __shared__ float part[2][8][64];      // 2 x 2 KB partial h-sums

    const int p = blockIdx.x;
    const int xb = (p & 7) * 64 + (p >> 3);    // XCD swizzle (512 % 8 == 0)
    const int tid = threadIdx.x;
    const int w = tid >> 6, l = tid & 63, g = l >> 4, c = l & 15;
    const int b = xb >> 2;
    const f32x4 z4 = {0.f, 0.f, 0.f, 0.f};

    // ---- hoisted invariants ----
    bf16x8 wf[2];                          // W1e frags, ht = 2w, 2w+1
    #pragma unroll
    for (int z = 0; z < 2; ++z)
        wf[z] = *(const bf16x8*)&W1ef[((2 * w + z) * 64 + l) * 8];

    bf16x8 pjb[4];                         // Pj octets: block-invariant (b fixed)
    #pragma unroll
    for (int pt = 0; pt < 4; ++pt)
        pjb[pt] = *(const bf16x8*)&Pjb[((long)(b * 64 + 16 * pt + c)) * 256
                                       + 32 * w + 8 * g];

    const float bias3 = b3[0];

    // stage mapping: tid<256 stages unit u=tid: (spt, sg, sc)
    const int spt = tid >> 6, sg = (tid >> 4) & 3, sc = tid & 15;
    const long erowbase = (long)xb * 1024 + 16 * spt + sc;

    f32x4 es0, es1;                        // in-flight staged edges
    if (tid < 256) {
        const float* ep = edges + erowbase * 32 + 8 * sg;
        es0 = *(const f32x4*)ep; es1 = *(const f32x4*)(ep + 4);
    }
    const float* PiB = Pi + ((long)xb * 16) * 256 + 32 * w + 8 * g;
    f32x4 pva0 = *(const f32x4*)PiB;       // Pi octet for batch 0
    f32x4 pva1 = *(const f32x4*)(PiB + 4);

    if (tid < 256) {                       // write batch-0 edges
        bf16x8 ev;
        #pragma unroll
        for (int j = 0; j < 4; ++j) { ev[j] = (bf16_t)es0[j]; ev[4 + j] = (bf16_t)es1[j]; }
        *(bf16x8*)&elds[0][tid * 8] = ev;
    }
    __syncthreads();

    f32x4 pvb0, pvb1;

    for (int t = 0; t < 16; ++t) {
        const int cur = t & 1;

        // issue next batch's loads early (hidden under L1+L2 of batch t)
        if (t < 15) {
            if (tid < 256) {
                const float* ep = edges + (erowbase + 64 * (t + 1)) * 32 + 8 * sg;
                es0 = *(const f32x4*)ep; es1 = *(const f32x4*)(ep + 4);
            }
            const float* pp = PiB + (t + 1) * 256;
            pvb0 = *(const f32x4*)pp; pvb1 = *(const f32x4*)(pp + 4);
        }

        // ---------------- layer 1 (sigma-fused, reg -> LDS octets) ----------
        {
            bf16x8 ebf[4];
            #pragma unroll
            for (int pt = 0; pt < 4; ++pt)
                ebf[pt] = *(const bf16x8*)&elds[cur][(pt * 64 + l) * 8];
            #pragma unroll
            for (int pt = 0; pt < 4; ++pt) {
                bf16x8 o;
                #pragma unroll
                for (int z = 0; z < 2; ++z) {
                    f32x4 a = mfma16(wf[z], ebf[pt], z4);
                    f32x4 pv = z ? pva1 : pva0;
                    #pragma unroll
                    for (int r = 0; r < 4; ++r) {
                        float v = a[r] + pv[r] + (float)pjb[pt][4 * z + r];
                        v = v > 0.f ? v : 0.f;
                        o[4 * z + r] = (bf16_t)v;
                    }
                }
                *(bf16x8*)&a1f[cur][((pt * 8 + w) * 64 + l) * 8] = o;
            }
        }

        // write-late: staged edges for batch t+1 into the other elds buffer
        if (t < 15 && tid < 256) {
            bf16x8 ev;
            #pragma unroll
            for (int j = 0; j < 4; ++j) { ev[j] = (bf16_t)es0[j]; ev[4 + j] = (bf16_t)es1[j]; }
            *(bf16x8*)&elds[cur ^ 1][tid * 8] = ev;
        }
        __syncthreads();                   // the one barrier per batch

        // deferred out-write for batch t-1 (all waves' part complete)
        if (t > 0 && tid < 64) {
            float s = bias3;
            #pragma unroll
            for (int ww = 0; ww < 8; ++ww) s += part[cur ^ 1][ww][tid];
            out[(long)xb * 1024 + (t - 1) * 64 + tid] = s;
        }

        // ---------------- layer 2 + layer 3 ----------------
        {
            f32x4 acc2[4][2];
            #pragma unroll
            for (int pt = 0; pt < 4; ++pt) { acc2[pt][0] = z4; acc2[pt][1] = z4; }
            #pragma unroll
            for (int ks = 0; ks < 8; ++ks) {
                bf16x8 af[4];
                #pragma unroll
                for (int pt = 0; pt < 4; ++pt)
                    af[pt] = *(const bf16x8*)&a1f[cur][((pt * 8 + ks) * 64 + l) * 8];
                #pragma unroll
                for (int cc = 0; cc < 2; ++cc) {
                    bf16x8 w2 = *(const bf16x8*)&W2f[((ks * 16 + 2 * w + cc) * 64 + l) * 8];
                    #pragma unroll
                    for (int pt = 0; pt < 4; ++pt)
                        acc2[pt][cc] = mfma16(w2, af[pt], acc2[pt][cc]);
                }
            }
            // L3: col = 32w + 16cc + 4g + r (in-lane), pair = 16pt + c
            f32x4 b2q[2], w3q[2];
            #pragma unroll
            for (int cc = 0; cc < 2; ++cc) {
                b2q[cc] = *(const f32x4*)&b2[32 * w + 16 * cc + 4 * g];
                w3q[cc] = *(const f32x4*)&W3[32 * w + 16 * cc + 4 * g];
            }
            #pragma unroll
            for (int pt = 0; pt < 4; ++pt) {
                float s = 0.f;
                #pragma unroll
                for (int cc = 0; cc < 2; ++cc)
                    #pragma unroll
                    for (int r = 0; r < 4; ++r) {
                        float v = acc2[pt][cc][r] + b2q[cc][r];
                        v = v > 0.f ? v : 0.f;
                        s = fmaf(v, w3q[cc][r], s);
                    }
                s += __shfl_xor(s, 16);    // sum the 4 g-groups
                s += __shfl_xor(s, 32);
                if (g == 0) part[cur][w][pt * 16 + c] = s;
            }
        }
        pva0 = pvb0; pva1 = pvb1;
    }

    __syncthreads();
    if (tid < 64) {                        // out for batch 15
        float s = bias3;
        #pragma unroll
        for (int ww = 0; ww < 8; ++ww) s += part[1][ww][tid];
        out[(long)xb * 1024 + 15 * 64 + tid] = s;
    }
}

extern "C" void kernel_launch(void* const* d_in, const int* in_sizes, int n_in,
                              void* d_out, int out_size, void* d_ws, size_t ws_size,
                              hipStream_t stream) {
    const float* nodes = (const float*)d_in[0];
    const float* edges = (const float*)d_in[1];
    const float* W1    = (const float*)d_in[2];
    const float* b1    = (const float*)d_in[3];
    const float* W2    = (const float*)d_in[4];
    const float* b2    = (const float*)d_in[5];
    const float* W3    = (const float*)d_in[6];
    const float* b3    = (const float*)d_in[7];
    float* out = (float*)d_out;

    char* ws = (char*)d_ws;
    float*  Pi   = (float*)ws;                                        // 8 MB
    bf16_t* Pjb  = (bf16_t*)(ws + (size_t)8 * 1024 * 1024);           // 4 MB
    bf16_t* W2f  = (bf16_t*)(ws + (size_t)12 * 1024 * 1024);          // 128 KB
    bf16_t* W1ef = (bf16_t*)(ws + (size_t)12 * 1024 * 1024 + 131072); // 16 KB

    prep_pack<<<dim3(36), dim3(256), 0, stream>>>(W1, W2, W1ef, W2f);
    prep_pij<<<dim3(1024), dim3(256), 0, stream>>>(nodes, W1, b1, Pi, Pjb);
    mlp_main<<<dim3(512), dim3(512), 0, stream>>>(edges, Pi, Pjb, W1ef, W2f, b2, W3, b3, out);
}